// Round 8
// baseline (311.270 us; speedup 1.0000x reference)
//
#include <hip/hip_runtime.h>
#include <stdint.h>

#define DEV __device__ __forceinline__

typedef unsigned short u16;
typedef __bf16 bf16x8 __attribute__((ext_vector_type(8)));
typedef float floatx4 __attribute__((ext_vector_type(4)));
typedef unsigned short u16x4 __attribute__((ext_vector_type(4)));
typedef unsigned short u16x8 __attribute__((ext_vector_type(8)));
typedef short s16x4 __attribute__((ext_vector_type(4)));

// Problem constants
// B=16, DIM=512, RES(L)=1024, NUM_HEADS=8, KEY_DIM=32, D=128, NH_KD=256, DH=1024, H_QKV=1536

DEV u16 f2bf(float x) {
  union { float f; uint32_t u; } v; v.f = x;
  uint32_t r = v.u + 0x7FFFu + ((v.u >> 16) & 1u);
  return (u16)(r >> 16);
}
DEV float bf2f(u16 x) {
  union { uint32_t u; float f; } v; v.u = ((uint32_t)x) << 16;
  return v.f;
}
DEV float loadf(const void* p, int i, int bf) {
  return bf ? bf2f(((const u16*)p)[i]) : ((const float*)p)[i];
}
DEV u16 fastbf(float x) {  // round-half-up truncation; ample tolerance
  union { float f; uint32_t u; } v; v.f = x;
  return (u16)((v.u + 0x8000u) >> 16);
}

DEV floatx4 mfma16(bf16x8 a, bf16x8 b, floatx4 c) {
  return __builtin_amdgcn_mfma_f32_16x16x32_bf16(a, b, c, 0, 0, 0);
}

DEV void gl_lds16(const void* g, void* l) {
  __builtin_amdgcn_global_load_lds(
      (const __attribute__((address_space(1))) void*)g,
      (__attribute__((address_space(3))) void*)l, 16, 0, 0);
}

// ---------------------------------------------------------------- dtype sniff
__global__ void sniff(const uint32_t* __restrict__ x, int* __restrict__ flag) {
  int lane = threadIdx.x & 63;
  int hits = 0;
#pragma unroll
  for (int i = 0; i < 4; ++i) {
    uint32_t u = x[lane * 4 + i];
    int e = (u >> 7) & 0xFF;
    hits += (e >= 100 && e <= 140) ? 1 : 0;
  }
  unsigned long long m = __ballot(hits >= 3);
  if (lane == 0) *flag = (__popcll(m) >= 40) ? 1 : 0;
}

// ---------------------------------------------------------------- convert (fused)
// ranges: w_qkv 786432 | w_proj 524288 | w_dw 768 | abias 8192
__global__ __launch_bounds__(256) void cvt_all(
    const void* __restrict__ a, const void* __restrict__ b,
    const void* __restrict__ c, const void* __restrict__ d,
    u16* __restrict__ oa, u16* __restrict__ ob, u16* __restrict__ oc,
    u16* __restrict__ od, const int* __restrict__ flag) {
  int i = blockIdx.x * 256 + threadIdx.x;
  int bf = *flag;
  if (i < 786432) {
    oa[i] = bf ? ((const u16*)a)[i] : f2bf(((const float*)a)[i]);
  } else if (i < 1310720) {
    int j = i - 786432;
    ob[j] = bf ? ((const u16*)b)[j] : f2bf(((const float*)b)[j]);
  } else if (i < 1311488) {
    int j = i - 1310720;
    oc[j] = bf ? ((const u16*)c)[j] : f2bf(((const float*)c)[j]);
  } else if (i < 1319680) {
    int j = i - 1311488;
    od[j] = bf ? ((const u16*)d)[j] : f2bf(((const float*)d)[j]);
  }
}

// ---------------------------------------------------------------- params
// scl/shf layout: [0..1535] qkv, [1536..1791] dw, [1792..2303] proj
__global__ __launch_bounds__(256) void prep_params(
    const void* qg, const void* qb, const void* qm, const void* qv,
    const void* dg, const void* db, const void* dm, const void* dv,
    const void* pg, const void* pb, const void* pm, const void* pv,
    float* scl, float* shf, const int* __restrict__ flag) {
  int i = blockIdx.x * 256 + threadIdx.x;
  if (i >= 2304) return;
  int bf = *flag;
  float g, b, m, v;
  if (i < 1536)      { g = loadf(qg, i, bf); b = loadf(qb, i, bf); m = loadf(qm, i, bf); v = loadf(qv, i, bf); }
  else if (i < 1792) { int j = i - 1536; g = loadf(dg, j, bf); b = loadf(db, j, bf); m = loadf(dm, j, bf); v = loadf(dv, j, bf); }
  else               { int j = i - 1792; g = loadf(pg, j, bf); b = loadf(pb, j, bf); m = loadf(pm, j, bf); v = loadf(pv, j, bf); }
  float s = g / sqrtf(v + 1e-5f);
  scl[i] = s;
  shf[i] = b - m * s;
}

// ---------------------------------------------------------------- transpose x
// x (16,512,1024) fp32-or-bf16 -> xT (16,1024,512) bf16, 64x64 tiles
__global__ __launch_bounds__(256) void transpose_x(const void* __restrict__ x,
                                                   u16* __restrict__ xT,
                                                   const int* __restrict__ flag) {
  __shared__ __align__(16) u16 tile[64 * 72];
  const int tid = threadIdx.x;
  const int b = blockIdx.z, c0 = blockIdx.y * 64, l0 = blockIdx.x * 64;
  const int bf = *flag;
  const size_t base = ((size_t)b * 512 + c0) * 1024 + l0;
  if (bf) {
    const u16* xb = (const u16*)x + base;
#pragma unroll
    for (int it = 0; it < 4; ++it) {
      int flat = it * 256 + tid;
      int row = flat >> 4, c4 = flat & 15;
      u16x4 v = *(const u16x4*)(xb + (size_t)row * 1024 + c4 * 4);
      tile[(c4 * 4 + 0) * 72 + row] = v.x;
      tile[(c4 * 4 + 1) * 72 + row] = v.y;
      tile[(c4 * 4 + 2) * 72 + row] = v.z;
      tile[(c4 * 4 + 3) * 72 + row] = v.w;
    }
  } else {
    const float* xb = (const float*)x + base;
#pragma unroll
    for (int it = 0; it < 4; ++it) {
      int flat = it * 256 + tid;
      int row = flat >> 4, c4 = flat & 15;
      floatx4 v = *(const floatx4*)(xb + (size_t)row * 1024 + c4 * 4);
      tile[(c4 * 4 + 0) * 72 + row] = f2bf(v[0]);
      tile[(c4 * 4 + 1) * 72 + row] = f2bf(v[1]);
      tile[(c4 * 4 + 2) * 72 + row] = f2bf(v[2]);
      tile[(c4 * 4 + 3) * 72 + row] = f2bf(v[3]);
    }
  }
  __syncthreads();
  u16* xTb = xT + ((size_t)b * 1024 + l0) * 512 + c0;
#pragma unroll
  for (int it = 0; it < 4; ++it) {
    int flat = it * 256 + tid;
    int row = flat >> 4, c4 = flat & 15;
    u16x4 v = *(const u16x4*)&tile[row * 72 + c4 * 4];
    *(u16x4*)(xTb + (size_t)row * 512 + c4 * 4) = v;
  }
}

// ---------------------------------------------------------------- GEMM + BN
// Y[b,o,l] = BN(sum_c A[o,c]*BT[b,l,c]).  A (M,K) bf16, BT (16,1024,K) bf16.
// 128x128 tile, BK=32, 4 waves each 64x64, m97-style global_load_lds staging.
template <int K>
__global__ __launch_bounds__(256) void gemm_bn(
    const u16* __restrict__ A, const u16* __restrict__ BT, u16* __restrict__ Y,
    const float* __restrict__ scl, const float* __restrict__ shf, int sclOff,
    const int* __restrict__ flag, int outFlagged) {
  __shared__ __align__(16) u16 lds[4 * 64 * 72];  // 36864 B
  const int tid = threadIdx.x, lane = tid & 63, w = tid >> 6;
  const int l15 = lane & 15, quad = lane >> 4;
  const int o_blk = blockIdx.y * 128, l_blk = blockIdx.x * 128, b = blockIdx.z;
  const int o_off = (w >> 1) * 64, l_off = (w & 1) * 64;
  const u16* BTb = BT + (size_t)b * 1024 * K;

  floatx4 acc[4][4];
#pragma unroll
  for (int i = 0; i < 4; ++i)
#pragma unroll
    for (int j = 0; j < 4; ++j) acc[i][j] = (floatx4){0.f, 0.f, 0.f, 0.f};

  for (int k0 = 0; k0 < K; k0 += 32) {
    __syncthreads();
#pragma unroll
    for (int s = 0; s < 2; ++s) {
      const int chunk = (s * 4 + w) * 1024;          // wave-uniform LDS byte base
      const int byteoff = chunk + lane * 16;
      const int row = byteoff >> 6;                  // 64 B per tile row (32 bf16)
      const int col = (byteoff & 63) >> 1;
      gl_lds16(A + (size_t)(o_blk + row) * K + k0 + col, &lds[chunk >> 1]);
      gl_lds16(BTb + (size_t)(l_blk + row) * K + k0 + col, &lds[4096 + (chunk >> 1)]);
    }
    __syncthreads();
    bf16x8 af[4], bfr[4];
#pragma unroll
    for (int ir = 0; ir < 4; ++ir)
      af[ir] = *(const bf16x8*)&lds[(o_off + 16 * ir + l15) * 32 + quad * 8];
#pragma unroll
    for (int jc = 0; jc < 4; ++jc)
      bfr[jc] = *(const bf16x8*)&lds[4096 + (l_off + 16 * jc + l15) * 32 + quad * 8];
#pragma unroll
    for (int ir = 0; ir < 4; ++ir)
#pragma unroll
      for (int jc = 0; jc < 4; ++jc)
        acc[ir][jc] = mfma16(af[ir], bfr[jc], acc[ir][jc]);
  }
  __syncthreads();
  // epilogue: BN, bf16, bounce through LDS for coalesced stores
  u16* eb = &lds[w * 4608];  // 64 x 72 u16 per wave
#pragma unroll
  for (int ir = 0; ir < 4; ++ir) {
#pragma unroll
    for (int r = 0; r < 4; ++r) {
      int rloc = 16 * ir + quad * 4 + r;
      int o = o_blk + o_off + rloc;
      float s = scl[sclOff + o], hh = shf[sclOff + o];
#pragma unroll
      for (int jc = 0; jc < 4; ++jc)
        eb[rloc * 72 + 16 * jc + l15] = f2bf(acc[ir][jc][r] * s + hh);
    }
  }
  asm volatile("s_waitcnt lgkmcnt(0)" ::: "memory");
  const int M = gridDim.y * 128;
  const size_t ybase = ((size_t)b * M + o_blk + o_off) * 1024 + l_blk + l_off;
  const int outbf = outFlagged ? *flag : 1;
  if (outbf) {
#pragma unroll
    for (int it = 0; it < 8; ++it) {
      int flat = it * 64 + lane;
      int row = flat >> 3, g = flat & 7;
      u16x8 v = *(const u16x8*)&eb[row * 72 + g * 8];
      *(u16x8*)(Y + ybase + (size_t)row * 1024 + g * 8) = v;
    }
  } else {
    float* Yf = (float*)Y;
#pragma unroll
    for (int it = 0; it < 8; ++it) {
      int flat = it * 64 + lane;
      int row = flat >> 3, g = flat & 7;
      u16x8 v = *(const u16x8*)&eb[row * 72 + g * 8];
      floatx4 lo, hi;
#pragma unroll
      for (int t = 0; t < 4; ++t) { lo[t] = bf2f(v[t]); hi[t] = bf2f(v[4 + t]); }
      *(floatx4*)(Yf + ybase + (size_t)row * 1024 + g * 8) = lo;
      *(floatx4*)(Yf + ybase + (size_t)row * 1024 + g * 8 + 4) = hi;
    }
  }
}

// ---------------------------------------------------------------- dwconv q + pack q,k
__global__ __launch_bounds__(256) void dwconv_pack(
    const u16* __restrict__ qkv, const u16* __restrict__ w_dw,
    const float* __restrict__ scl, const float* __restrict__ shf,
    u16* __restrict__ qT, u16* __restrict__ kT) {
  __shared__ __align__(16) u16 lds[256 * 36];
  const int tid = threadIdx.x;
  const int lch = blockIdx.x, h = blockIdx.y, b = blockIdx.z;
  const int r = tid >> 3, seg = tid & 7;
  const int l0 = lch * 256 + seg * 32;
  {  // q: conv3 + BN, write transposed to LDS
    const int o = h * 32 + r;
    const u16* base = qkv + ((size_t)b * 1536 + o) * 1024;
    float w0 = bf2f(w_dw[o * 3 + 0]), w1 = bf2f(w_dw[o * 3 + 1]), w2 = bf2f(w_dw[o * 3 + 2]);
    float sc = scl[1536 + o], sh = shf[1536 + o];
    float prev = (l0 > 0) ? bf2f(base[l0 - 1]) : 0.f;
    float cur = bf2f(base[l0]);
#pragma unroll 4
    for (int j = 0; j < 32; ++j) {
      int lg = l0 + j;
      float nxt = (lg + 1 < 1024) ? bf2f(base[lg + 1]) : 0.f;
      lds[(seg * 32 + j) * 36 + r] = f2bf((w0 * prev + w1 * cur + w2 * nxt) * sc + sh);
      prev = cur; cur = nxt;
    }
  }
  __syncthreads();
  {
    const size_t qTb = (((size_t)b * 8 + h) * 1024 + lch * 256) * 32;
#pragma unroll
    for (int it = 0; it < 8; ++it) {
      int flat = it * 256 + tid;
      int ll = flat >> 3, g = flat & 7;
      u16x4 v = *(const u16x4*)&lds[ll * 36 + g * 4];
      *(u16x4*)(qT + qTb + (size_t)ll * 32 + g * 4) = v;
    }
  }
  __syncthreads();
  {  // k: pure transpose
    const int o = 256 + h * 32 + r;
    const u16* base = qkv + ((size_t)b * 1536 + o) * 1024;
#pragma unroll 8
    for (int j = 0; j < 32; ++j) lds[(seg * 32 + j) * 36 + r] = base[l0 + j];
  }
  __syncthreads();
  {
    const size_t kTb = (((size_t)b * 8 + h) * 1024 + lch * 256) * 32;
#pragma unroll
    for (int it = 0; it < 8; ++it) {
      int flat = it * 256 + tid;
      int ll = flat >> 3, g = flat & 7;
      u16x4 v = *(const u16x4*)&lds[ll * 36 + g * 4];
      *(u16x4*)(kT + kTb + (size_t)ll * 32 + g * 4) = v;
    }
  }
}

// ---------------------------------------------------------------- flash attention
// R8: break the phase-lockstep.  R7's evidence: removing ~8us VALU + all
// bank conflicts made it SLOWER (79->84.5) while no pipe exceeded 33% =>
// the wall is that barriers keep all resident waves in the same phase
// (QK / exp / PV execute in lockstep; total = SUM of phase times, ~80us,
// instead of MAX, ~30us).  Fix: shrink the sync domain.  Block = 256 thr
// / 4 waves / 64 n-rows (grid 2048).  LDS/block = 8KB bias + 2x8KB V
// double-buffer = 24KB -> ~6 independent blocks/CU (was ~1.6 of 512-thr),
// occupancy ~75%: each SIMD co-schedules waves of ~6 blocks at
// uncorrelated phases, so QK/exp/PV from different blocks overlap pipes.
// Same math, same conflict-free fragment-major V layout, same gl_lds
// staging (wave w stages its two d-blocks 2w, 2w+1).
__global__ __launch_bounds__(256, 4) void attn(
    const u16* __restrict__ qT, const u16* __restrict__ kT,
    const u16* __restrict__ qkv, const u16* __restrict__ ab,
    u16* __restrict__ OT) {
  __shared__ __align__(16) float biasE[2048];    // 8 KB
  __shared__ __align__(16) u16 ldsV[8192];       // 2 bufs x 4096 u16 (32m x 128d)
  const int tid = threadIdx.x, lane = tid & 63, w = tid >> 6;  // w in 0..3
  const int l15 = lane & 15, quad = lane >> 4;
  const int id = blockIdx.x;
  const int pair = id & 127, nb = id >> 7;     // 0..15; id%8 == h -> same-XCD (b,h)
  const int b = pair >> 3, h = pair & 7;
  for (int i = tid; i < 2048; i += 256) {
    int dd = i - 1024;
    int idx = dd < 0 ? -dd : dd;
    if (idx > 1023) idx = 1023;
    biasE[i] = bf2f(ab[h * 1024 + idx]) * 1.44269504088896340f;
  }
  const int n0 = nb * 64 + w * 16;
  const size_t bh = ((size_t)b * 8 + h) * 1024;
  const u16* kTb = kT + bh * 32;
  const u16* vb = qkv + ((size_t)b * 1536 + 512 + h * 128) * 1024;
  const bf16x8 qf = *(const bf16x8*)(qT + bh * 32 + (size_t)(n0 + l15) * 32 + quad * 8);
  // permuted K-row fragment pointers: kf0 rows 8*(l15/4)+(l15%4), kf1 = +4
  // -> S C/D regs land as m = 8q+r (s0) / 8q+4+r (s1): the K=32 B-frag order.
  const int prow = 8 * (l15 >> 2) + (l15 & 3);
  const u16* kfp0 = kTb + (size_t)prow * 32 + quad * 8;
  const u16* kfp1 = kfp0 + 4 * 32;
  // V gl_lds staging: wave w owns d-blocks 2w and 2w+1.  Per-lane global src
  // rows 32w+l15 / 32w+16+l15, m-offset 8*quad; LDS dst wave-uniform.
  const u16* vsrc0 = vb + (size_t)(32 * w + l15) * 1024 + 8 * quad;
  const u16* vsrc1 = vsrc0 + 16 * 1024;
  // read base (u16 idx within buffer): block jd at jd*512, slot quad*16+l15
  const int vrd = quad * 128 + l15 * 8;

  floatx4 oacc[8];
#pragma unroll
  for (int j = 0; j < 8; ++j) oacc[j] = (floatx4){0.f, 0.f, 0.f, 0.f};
  float rsA = 0.f, rsB = 0.f;
  constexpr float c1 = 0.17677669529663689f * 1.44269504088896340f;  // scale*log2e
  const floatx4 zf = (floatx4){0.f, 0.f, 0.f, 0.f};

  // stage one 32-m chunk into buffer buf (2 x gl_lds16 per wave)
  auto stage = [&](int buf, int mbase) {
    gl_lds16(vsrc0 + mbase, &ldsV[buf * 4096 + (2 * w) * 512]);
    gl_lds16(vsrc1 + mbase, &ldsV[buf * 4096 + (2 * w + 1) * 512]);
  };

  // prologue: K frags for chunk 0; stage chunk 0 into buf 0
  bf16x8 kc0 = *(const bf16x8*)(kfp0);
  bf16x8 kc1 = *(const bf16x8*)(kfp1);
  stage(0, 0);
  __syncthreads();  // biasE + chunk-0 staging complete (vmcnt drained)

#pragma unroll 1
  for (int m0 = 0; m0 < 1024; m0 += 32) {
    const int par = (m0 >> 5) & 1;
    const bool more = (m0 + 32) < 1024;
    if (more) stage(par ^ 1, m0 + 32);  // next chunk's DMA under this compute
    // S^T tiles (permuted rows): s0[r] -> m = m0+8q+r, s1[r] -> m = m0+8q+4+r
    floatx4 s0 = mfma16(kc0, qf, zf);
    floatx4 s1 = mfma16(kc1, qf, zf);
    if (more) {  // kc dead after QK issue; reload for next chunk
      kc0 = *(const bf16x8*)(kfp0 + (size_t)(m0 + 32) * 32);
      kc1 = *(const bf16x8*)(kfp1 + (size_t)(m0 + 32) * 32);
    }
    const int Cb = 1024 + n0 + l15 - 8 * quad - m0;
    bf16x8 pfb;
#pragma unroll
    for (int r = 0; r < 4; ++r) {
      float p0 = __builtin_amdgcn_exp2f(s0[r] * c1 + biasE[Cb - r]);
      float p1 = __builtin_amdgcn_exp2f(s1[r] * c1 + biasE[Cb - 4 - r]);
      rsA += p0;
      rsB += p1;
      pfb[r] = (__bf16)p0;
      pfb[4 + r] = (__bf16)p1;
    }
    const int rbase = par * 4096 + vrd;
#pragma unroll
    for (int jd = 0; jd < 8; ++jd) {
      bf16x8 vv = *(const bf16x8*)&ldsV[rbase + jd * 512];  // ds_read_b128
      oacc[jd] = mfma16(vv, pfb, oacc[jd]);                 // K=32 PV
    }
    __syncthreads();
  }
  // rowsum: quads partition m -> reduce across quads (lanes sharing l15)
  float rs = rsA + rsB;
  rs += __shfl_xor(rs, 16, 64);
  rs += __shfl_xor(rs, 32, 64);
  const float inv = __builtin_amdgcn_rcpf(rs);
  // O^T elem (d = 16jd + quad*4 + r, n = n0 + l15); OT (b, n, h*128+d)
  u16* OTb = OT + ((size_t)b * 1024 + n0 + l15) * 1024 + h * 128 + quad * 4;
#pragma unroll
  for (int jd = 0; jd < 8; ++jd) {
    u16x4 o;
#pragma unroll
    for (int r = 0; r < 4; ++r) {
      float v = oacc[jd][r] * inv;
      o[r] = fastbf(v > 0.f ? v : 0.f);
    }
    *(u16x4*)(OTb + 16 * jd) = o;
  }
}

// ---------------------------------------------------------------- launch
extern "C" void kernel_launch(void* const* d_in, const int* in_sizes, int n_in,
                              void* d_out, int out_size, void* d_ws, size_t ws_size,
                              hipStream_t stream) {
  const void* x      = d_in[0];
  const void* w_qkv  = d_in[1];
  const void* qkv_g  = d_in[2];
  const void* qkv_b  = d_in[3];
  const void* qkv_m  = d_in[4];
  const void* qkv_v  = d_in[5];
  const void* w_dw   = d_in[6];
  const void* dw_g   = d_in[7];
  const void* dw_b   = d_in[8];
  const void* dw_m   = d_in[9];
  const void* dw_v   = d_in[10];
  const void* w_proj = d_in[11];
  const void* proj_g = d_in[12];
  const void* proj_b = d_in[13];
  const void* proj_m = d_in[14];
  const void* proj_v = d_in[15];
  const void* abias  = d_in[16];

  char* ws = (char*)d_ws;
  u16*   xT      = (u16*)(ws);                   // 16,777,216 B
  u16*   qkv     = (u16*)(ws + 16777216);        // 50,331,648 B
  u16*   qT      = (u16*)(ws + 67108864);        //  8,388,608 B
  u16*   kT      = (u16*)(ws + 75497472);        //  8,388,608 B
  u16*   OT      = (u16*)(ws + 83886080);        // 33,554,432 B
  float* scl     = (float*)(ws + 117440512);     //      9,216 B
  float* shf     = (float*)(ws + 117449728);     //      9,216 B
  u16*   wqkv_c  = (u16*)(ws + 117458944);       //  1,572,864 B
  u16*   wproj_c = (u16*)(ws + 119031808);       //  1,048,576 B
  u16*   wdw_c   = (u16*)(ws + 120080384);       //      2,048 B
  u16*   ab_c    = (u16*)(ws + 120082432);       //     16,384 B
  int*   flag    = (int*)(ws + 120098816);       //         64 B
  if (ws_size < (size_t)120098880) return;

  sniff<<<1, 64, 0, stream>>>((const uint32_t*)x, flag);
  cvt_all<<<5155, 256, 0, stream>>>(w_qkv, w_proj, w_dw, abias,
                                    wqkv_c, wproj_c, wdw_c, ab_c, flag);
  prep_params<<<9, 256, 0, stream>>>(qkv_g, qkv_b, qkv_m, qkv_v, dw_g, dw_b, dw_m,
                                     dw_v, proj_g, proj_b, proj_m, proj_v, scl, shf, flag);
  transpose_x<<<dim3(16, 8, 16), 256, 0, stream>>>(x, xT, flag);
  gemm_bn<512><<<dim3(8, 12, 16), 256, 0, stream>>>(wqkv_c, xT, qkv, scl, shf, 0, flag, 0);
  dwconv_pack<<<dim3(4, 8, 16), 256, 0, stream>>>(qkv, wdw_c, scl, shf, qT, kT);
  attn<<<2048, 256, 0, stream>>>(qT, kT, qkv, ab_c, OT);
  gemm_bn<1024><<<dim3(8, 4, 16), 256, 0, stream>>>(wproj_c, OT, (u16*)d_out, scl, shf, 1792, flag, 1);
}

// Round 9
// 271.501 us; speedup vs baseline: 1.1465x; 1.1465x over previous
//
#include <hip/hip_runtime.h>
#include <stdint.h>

#define DEV __device__ __forceinline__

typedef unsigned short u16;
typedef __bf16 bf16x8 __attribute__((ext_vector_type(8)));
typedef float floatx4 __attribute__((ext_vector_type(4)));
typedef unsigned short u16x4 __attribute__((ext_vector_type(4)));
typedef unsigned short u16x8 __attribute__((ext_vector_type(8)));
typedef short s16x4 __attribute__((ext_vector_type(4)));

// Problem constants
// B=16, DIM=512, RES(L)=1024, NUM_HEADS=8, KEY_DIM=32, D=128, NH_KD=256, DH=1024, H_QKV=1536

DEV u16 f2bf(float x) {
  union { float f; uint32_t u; } v; v.f = x;
  uint32_t r = v.u + 0x7FFFu + ((v.u >> 16) & 1u);
  return (u16)(r >> 16);
}
DEV float bf2f(u16 x) {
  union { uint32_t u; float f; } v; v.u = ((uint32_t)x) << 16;
  return v.f;
}
DEV float loadf(const void* p, int i, int bf) {
  return bf ? bf2f(((const u16*)p)[i]) : ((const float*)p)[i];
}
DEV u16 fastbf(float x) {  // round-half-up truncation; ample tolerance
  union { float f; uint32_t u; } v; v.f = x;
  return (u16)((v.u + 0x8000u) >> 16);
}
DEV bf16x8 u2b(u16x8 v) {
  union { u16x8 u; bf16x8 b; } x; x.u = v; return x.b;
}

DEV floatx4 mfma16(bf16x8 a, bf16x8 b, floatx4 c) {
  return __builtin_amdgcn_mfma_f32_16x16x32_bf16(a, b, c, 0, 0, 0);
}

DEV void gl_lds16(const void* g, void* l) {
  __builtin_amdgcn_global_load_lds(
      (const __attribute__((address_space(1))) void*)g,
      (__attribute__((address_space(3))) void*)l, 16, 0, 0);
}

// ---------------------------------------------------------------- dtype sniff
__global__ void sniff(const uint32_t* __restrict__ x, int* __restrict__ flag) {
  int lane = threadIdx.x & 63;
  int hits = 0;
#pragma unroll
  for (int i = 0; i < 4; ++i) {
    uint32_t u = x[lane * 4 + i];
    int e = (u >> 7) & 0xFF;
    hits += (e >= 100 && e <= 140) ? 1 : 0;
  }
  unsigned long long m = __ballot(hits >= 3);
  if (lane == 0) *flag = (__popcll(m) >= 40) ? 1 : 0;
}

// ---------------------------------------------------------------- convert (fused)
// ranges: w_qkv 786432 | w_proj 524288 | w_dw 768 | abias 8192
__global__ __launch_bounds__(256) void cvt_all(
    const void* __restrict__ a, const void* __restrict__ b,
    const void* __restrict__ c, const void* __restrict__ d,
    u16* __restrict__ oa, u16* __restrict__ ob, u16* __restrict__ oc,
    u16* __restrict__ od, const int* __restrict__ flag) {
  int i = blockIdx.x * 256 + threadIdx.x;
  int bf = *flag;
  if (i < 786432) {
    oa[i] = bf ? ((const u16*)a)[i] : f2bf(((const float*)a)[i]);
  } else if (i < 1310720) {
    int j = i - 786432;
    ob[j] = bf ? ((const u16*)b)[j] : f2bf(((const float*)b)[j]);
  } else if (i < 1311488) {
    int j = i - 1310720;
    oc[j] = bf ? ((const u16*)c)[j] : f2bf(((const float*)c)[j]);
  } else if (i < 1319680) {
    int j = i - 1311488;
    od[j] = bf ? ((const u16*)d)[j] : f2bf(((const float*)d)[j]);
  }
}

// ---------------------------------------------------------------- params
// scl/shf layout: [0..1535] qkv, [1536..1791] dw, [1792..2303] proj
__global__ __launch_bounds__(256) void prep_params(
    const void* qg, const void* qb, const void* qm, const void* qv,
    const void* dg, const void* db, const void* dm, const void* dv,
    const void* pg, const void* pb, const void* pm, const void* pv,
    float* scl, float* shf, const int* __restrict__ flag) {
  int i = blockIdx.x * 256 + threadIdx.x;
  if (i >= 2304) return;
  int bf = *flag;
  float g, b, m, v;
  if (i < 1536)      { g = loadf(qg, i, bf); b = loadf(qb, i, bf); m = loadf(qm, i, bf); v = loadf(qv, i, bf); }
  else if (i < 1792) { int j = i - 1536; g = loadf(dg, j, bf); b = loadf(db, j, bf); m = loadf(dm, j, bf); v = loadf(dv, j, bf); }
  else               { int j = i - 1792; g = loadf(pg, j, bf); b = loadf(pb, j, bf); m = loadf(pm, j, bf); v = loadf(pv, j, bf); }
  float s = g / sqrtf(v + 1e-5f);
  scl[i] = s;
  shf[i] = b - m * s;
}

// ---------------------------------------------------------------- transpose x
// x (16,512,1024) fp32-or-bf16 -> xT (16,1024,512) bf16, 64x64 tiles
__global__ __launch_bounds__(256) void transpose_x(const void* __restrict__ x,
                                                   u16* __restrict__ xT,
                                                   const int* __restrict__ flag) {
  __shared__ __align__(16) u16 tile[64 * 72];
  const int tid = threadIdx.x;
  const int b = blockIdx.z, c0 = blockIdx.y * 64, l0 = blockIdx.x * 64;
  const int bf = *flag;
  const size_t base = ((size_t)b * 512 + c0) * 1024 + l0;
  if (bf) {
    const u16* xb = (const u16*)x + base;
#pragma unroll
    for (int it = 0; it < 4; ++it) {
      int flat = it * 256 + tid;
      int row = flat >> 4, c4 = flat & 15;
      u16x4 v = *(const u16x4*)(xb + (size_t)row * 1024 + c4 * 4);
      tile[(c4 * 4 + 0) * 72 + row] = v.x;
      tile[(c4 * 4 + 1) * 72 + row] = v.y;
      tile[(c4 * 4 + 2) * 72 + row] = v.z;
      tile[(c4 * 4 + 3) * 72 + row] = v.w;
    }
  } else {
    const float* xb = (const float*)x + base;
#pragma unroll
    for (int it = 0; it < 4; ++it) {
      int flat = it * 256 + tid;
      int row = flat >> 4, c4 = flat & 15;
      floatx4 v = *(const floatx4*)(xb + (size_t)row * 1024 + c4 * 4);
      tile[(c4 * 4 + 0) * 72 + row] = f2bf(v[0]);
      tile[(c4 * 4 + 1) * 72 + row] = f2bf(v[1]);
      tile[(c4 * 4 + 2) * 72 + row] = f2bf(v[2]);
      tile[(c4 * 4 + 3) * 72 + row] = f2bf(v[3]);
    }
  }
  __syncthreads();
  u16* xTb = xT + ((size_t)b * 1024 + l0) * 512 + c0;
#pragma unroll
  for (int it = 0; it < 4; ++it) {
    int flat = it * 256 + tid;
    int row = flat >> 4, c4 = flat & 15;
    u16x4 v = *(const u16x4*)&tile[row * 72 + c4 * 4];
    *(u16x4*)(xTb + (size_t)row * 512 + c4 * 4) = v;
  }
}

// ---------------------------------------------------------------- GEMM + BN
// Y[b,o,l] = BN(sum_c A[o,c]*BT[b,l,c]).  A (M,K) bf16, BT (16,1024,K) bf16.
// Tile 128(M) x BN(N), BK=32, 4 waves, m97-style global_load_lds staging.
// BN=128: wave = 64x64 (acc 4x4).  BN=64: wave = 64x32 (acc 4x2) -- used for
// gemm2 where the 128x128 grid gave only 512 blocks = 2/CU = 25% occupancy
// cap; BN=64 doubles the grid to 1024 = 4/CU and shrinks LDS to 20KB.
template <int K, int BN>
__global__ __launch_bounds__(256) void gemm_bn(
    const u16* __restrict__ A, const u16* __restrict__ BT, u16* __restrict__ Y,
    const float* __restrict__ scl, const float* __restrict__ shf, int sclOff,
    const int* __restrict__ flag, int outFlagged) {
  constexpr int LDSZ = (BN == 128) ? 18432 : 10240;  // u16 count
  __shared__ __align__(16) u16 lds[LDSZ];
  const int tid = threadIdx.x, lane = tid & 63, w = tid >> 6;
  const int l15 = lane & 15, quad = lane >> 4;
  const int o_blk = blockIdx.y * 128, l_blk = blockIdx.x * BN, b = blockIdx.z;
  constexpr int NW = BN / 32;                 // 4 or 2 accumulator cols
  const int o_off = (BN == 128) ? (w >> 1) * 64 : (w >> 1) * 64;
  const int l_off = (BN == 128) ? (w & 1) * 64 : (w & 1) * 32;
  const u16* BTb = BT + (size_t)b * 1024 * K;

  floatx4 acc[4][NW];
#pragma unroll
  for (int i = 0; i < 4; ++i)
#pragma unroll
    for (int j = 0; j < NW; ++j) acc[i][j] = (floatx4){0.f, 0.f, 0.f, 0.f};

  for (int k0 = 0; k0 < K; k0 += 32) {
    __syncthreads();
    if constexpr (BN == 128) {
#pragma unroll
      for (int s = 0; s < 2; ++s) {
        const int chunk = (s * 4 + w) * 1024;        // wave-uniform LDS byte base
        const int byteoff = chunk + lane * 16;
        const int row = byteoff >> 6;                // 64 B per tile row (32 bf16)
        const int col = (byteoff & 63) >> 1;
        gl_lds16(A + (size_t)(o_blk + row) * K + k0 + col, &lds[chunk >> 1]);
        gl_lds16(BTb + (size_t)(l_blk + row) * K + k0 + col, &lds[4096 + (chunk >> 1)]);
      }
    } else {  // BN==64: 8 A-chunks + 4 B-chunks, flat over (s,w)
#pragma unroll
      for (int s = 0; s < 3; ++s) {
        const int c = s * 4 + w;
        if (c < 8) {
          const int byteoff = c * 1024 + lane * 16;
          const int row = byteoff >> 6;
          const int col = (byteoff & 63) >> 1;
          gl_lds16(A + (size_t)(o_blk + row) * K + k0 + col, &lds[c * 512]);
        } else {
          const int cb = c - 8;
          const int byteoff = cb * 1024 + lane * 16;
          const int row = byteoff >> 6;
          const int col = (byteoff & 63) >> 1;
          gl_lds16(BTb + (size_t)(l_blk + row) * K + k0 + col, &lds[4096 + cb * 512]);
        }
      }
    }
    __syncthreads();
    bf16x8 af[4], bfr[NW];
#pragma unroll
    for (int ir = 0; ir < 4; ++ir)
      af[ir] = *(const bf16x8*)&lds[(o_off + 16 * ir + l15) * 32 + quad * 8];
#pragma unroll
    for (int jc = 0; jc < NW; ++jc)
      bfr[jc] = *(const bf16x8*)&lds[4096 + (l_off + 16 * jc + l15) * 32 + quad * 8];
#pragma unroll
    for (int ir = 0; ir < 4; ++ir)
#pragma unroll
      for (int jc = 0; jc < NW; ++jc)
        acc[ir][jc] = mfma16(af[ir], bfr[jc], acc[ir][jc]);
  }
  __syncthreads();
  // epilogue: BN-apply, bf16, bounce through LDS for coalesced stores
  constexpr int EP = (BN == 128) ? 72 : 40;   // row pitch (u16)
  u16* eb = &lds[w * 64 * EP];
#pragma unroll
  for (int ir = 0; ir < 4; ++ir) {
#pragma unroll
    for (int r = 0; r < 4; ++r) {
      int rloc = 16 * ir + quad * 4 + r;
      int o = o_blk + o_off + rloc;
      float s = scl[sclOff + o], hh = shf[sclOff + o];
#pragma unroll
      for (int jc = 0; jc < NW; ++jc)
        eb[rloc * EP + 16 * jc + l15] = f2bf(acc[ir][jc][r] * s + hh);
    }
  }
  asm volatile("s_waitcnt lgkmcnt(0)" ::: "memory");
  const int M = gridDim.y * 128;
  const size_t ybase = ((size_t)b * M + o_blk + o_off) * 1024 + l_blk + l_off;
  const int outbf = outFlagged ? *flag : 1;
  constexpr int GN = BN / 2 / 8;              // u16x8 groups per wave row: 8 or 4
  constexpr int ITS = 64 * GN / 64;           // store iterations: 8 or 4
  if (outbf) {
#pragma unroll
    for (int it = 0; it < ITS; ++it) {
      int flat = it * 64 + lane;
      int row = flat / GN, g = flat % GN;
      u16x8 v = *(const u16x8*)&eb[row * EP + g * 8];
      *(u16x8*)(Y + ybase + (size_t)row * 1024 + g * 8) = v;
    }
  } else {
    float* Yf = (float*)Y;
#pragma unroll
    for (int it = 0; it < ITS; ++it) {
      int flat = it * 64 + lane;
      int row = flat / GN, g = flat % GN;
      u16x8 v = *(const u16x8*)&eb[row * EP + g * 8];
      floatx4 lo, hi;
#pragma unroll
      for (int t = 0; t < 4; ++t) { lo[t] = bf2f(v[t]); hi[t] = bf2f(v[4 + t]); }
      *(floatx4*)(Yf + ybase + (size_t)row * 1024 + g * 8) = lo;
      *(floatx4*)(Yf + ybase + (size_t)row * 1024 + g * 8 + 4) = hi;
    }
  }
}

// ---------------------------------------------------------------- dwconv q + pack q,k
__global__ __launch_bounds__(256) void dwconv_pack(
    const u16* __restrict__ qkv, const u16* __restrict__ w_dw,
    const float* __restrict__ scl, const float* __restrict__ shf,
    u16* __restrict__ qT, u16* __restrict__ kT) {
  __shared__ __align__(16) u16 lds[256 * 36];
  const int tid = threadIdx.x;
  const int lch = blockIdx.x, h = blockIdx.y, b = blockIdx.z;
  const int r = tid >> 3, seg = tid & 7;
  const int l0 = lch * 256 + seg * 32;
  {  // q: conv3 + BN, write transposed to LDS
    const int o = h * 32 + r;
    const u16* base = qkv + ((size_t)b * 1536 + o) * 1024;
    float w0 = bf2f(w_dw[o * 3 + 0]), w1 = bf2f(w_dw[o * 3 + 1]), w2 = bf2f(w_dw[o * 3 + 2]);
    float sc = scl[1536 + o], sh = shf[1536 + o];
    float prev = (l0 > 0) ? bf2f(base[l0 - 1]) : 0.f;
    float cur = bf2f(base[l0]);
#pragma unroll 4
    for (int j = 0; j < 32; ++j) {
      int lg = l0 + j;
      float nxt = (lg + 1 < 1024) ? bf2f(base[lg + 1]) : 0.f;
      lds[(seg * 32 + j) * 36 + r] = f2bf((w0 * prev + w1 * cur + w2 * nxt) * sc + sh);
      prev = cur; cur = nxt;
    }
  }
  __syncthreads();
  {
    const size_t qTb = (((size_t)b * 8 + h) * 1024 + lch * 256) * 32;
#pragma unroll
    for (int it = 0; it < 8; ++it) {
      int flat = it * 256 + tid;
      int ll = flat >> 3, g = flat & 7;
      u16x4 v = *(const u16x4*)&lds[ll * 36 + g * 4];
      *(u16x4*)(qT + qTb + (size_t)ll * 32 + g * 4) = v;
    }
  }
  __syncthreads();
  {  // k: pure transpose
    const int o = 256 + h * 32 + r;
    const u16* base = qkv + ((size_t)b * 1536 + o) * 1024;
#pragma unroll 8
    for (int j = 0; j < 32; ++j) lds[(seg * 32 + j) * 36 + r] = base[l0 + j];
  }
  __syncthreads();
  {
    const size_t kTb = (((size_t)b * 8 + h) * 1024 + lch * 256) * 32;
#pragma unroll
    for (int it = 0; it < 8; ++it) {
      int flat = it * 256 + tid;
      int ll = flat >> 3, g = flat & 7;
      u16x4 v = *(const u16x4*)&lds[ll * 36 + g * 4];
      *(u16x4*)(kT + kTb + (size_t)ll * 32 + g * 4) = v;
    }
  }
}

// ---------------------------------------------------------------- flash attention
// R9 attn = exact R4 revert (best measured: 79.6us).  R5-R8 established:
// barrier-free -> L2 thrash (+193us); gl_lds V-staging + fewer barriers ->
// +5us; smaller blocks -> 2x V traffic (+40us).  R4's reg-staged ds_write
// pipeline with 32 barriers and conflict-free fragment-major V layout wins.
__global__ __launch_bounds__(512, 4) void attn(
    const u16* __restrict__ qT, const u16* __restrict__ kT,
    const u16* __restrict__ qkv, const u16* __restrict__ ab,
    u16* __restrict__ OT) {
  __shared__ __align__(16) float biasE[2048];
  __shared__ __align__(16) u16 ldsV[2 * 4096];  // 2 bufs x 8 blocks x 512 u16
  const int tid = threadIdx.x, lane = tid & 63, w = tid >> 6;  // w in 0..7
  const int l15 = lane & 15, quad = lane >> 4;
  const int id = blockIdx.x;
  const int pair = id & 127, nb = id >> 7;     // id%8 == h -> same-XCD for (b,h)
  const int b = pair >> 3, h = pair & 7;
  for (int i = tid; i < 2048; i += 512) {
    int dd = i - 1024;
    int idx = dd < 0 ? -dd : dd;
    if (idx > 1023) idx = 1023;
    biasE[i] = bf2f(ab[h * 1024 + idx]) * 1.44269504088896340f;
  }
  const int n0 = nb * 128 + w * 16;
  const size_t bh = ((size_t)b * 8 + h) * 1024;
  const u16* kTb = kT + bh * 32;
  const u16* vb = qkv + ((size_t)b * 1536 + 512 + h * 128) * 1024;
  const bf16x8 qf = *(const bf16x8*)(qT + bh * 32 + (size_t)(n0 + l15) * 32 + quad * 8);
  // permuted K-row fragment pointers: kf0 rows 8*(l15/4)+(l15%4), kf1 = +4
  // -> S C/D regs land as m = 8q+r (s0) / 8q+4+r (s1): the K=32 B-frag order.
  const int prow = 8 * (l15 >> 2) + (l15 & 3);
  const u16* kfp0 = kTb + (size_t)prow * 32 + quad * 8;
  const u16* kfp1 = kfp0 + 4 * 32;
  // V staging: tid covers (d = tid/4, m-octet sc = tid%4); 512x16B = 8KB/chunk
  const int sd = tid >> 2, sc = tid & 3;
  const u16* sg = vb + (size_t)sd * 1024 + sc * 8;
  // write slot: block (sd>>4), slot sc*16 + (sd&15)  [16B-aligned]
  const int wv = (sd >> 4) * 512 + (sc * 16 + (sd & 15)) * 8;
  // read base: block jd (+jd*512), slot quad*16 + l15
  const int vrd = quad * 128 + l15 * 8;

  floatx4 oacc[8];
#pragma unroll
  for (int j = 0; j < 8; ++j) oacc[j] = (floatx4){0.f, 0.f, 0.f, 0.f};
  float rs = 0.f;
  constexpr float c1 = 0.17677669529663689f * 1.44269504088896340f;  // scale*log2e
  const floatx4 zf = (floatx4){0.f, 0.f, 0.f, 0.f};

  // prologue: stage V chunk m=0 into buffer 0; load K frags for chunk 0
  bf16x8 kc0 = *(const bf16x8*)(kfp0);
  bf16x8 kc1 = *(const bf16x8*)(kfp1);
  {
    u16x8 a = *(const u16x8*)sg;
    *(u16x8*)&ldsV[wv] = a;  // ds_write_b128
  }
  __syncthreads();

#pragma unroll 1
  for (int m0 = 0; m0 < 1024; m0 += 32) {
    const int par = (m0 >> 5) & 1;
    const bool more = (m0 + 32) < 1024;
    u16x8 a;
    bf16x8 kn0, kn1;
    if (more) {  // prefetch next chunk's V (global->reg) and K frags
      a = *(const u16x8*)(sg + m0 + 32);
      kn0 = *(const bf16x8*)(kfp0 + (size_t)(m0 + 32) * 32);
      kn1 = *(const bf16x8*)(kfp1 + (size_t)(m0 + 32) * 32);
    }
    // S^T tiles (permuted rows): s0[r] -> m = m0+8q+r, s1[r] -> m = m0+8q+4+r
    floatx4 s0 = mfma16(kc0, qf, zf);
    floatx4 s1 = mfma16(kc1, qf, zf);
    const int Cb = 1024 + n0 + l15 - 8 * quad - m0;
    u16x8 pf;
#pragma unroll
    for (int r = 0; r < 4; ++r) {
      float p0 = __builtin_amdgcn_exp2f(s0[r] * c1 + biasE[Cb - r]);
      float p1 = __builtin_amdgcn_exp2f(s1[r] * c1 + biasE[Cb - 4 - r]);
      rs += p0 + p1;
      pf[r] = fastbf(p0);
      pf[4 + r] = fastbf(p1);
    }
    const bf16x8 pfb = u2b(pf);
    const int rbase = par * 4096 + vrd;
#pragma unroll
    for (int jd = 0; jd < 8; ++jd) {
      bf16x8 vv = *(const bf16x8*)&ldsV[rbase + jd * 512];  // ds_read_b128
      oacc[jd] = mfma16(vv, pfb, oacc[jd]);                 // K=32 PV
    }
    if (more) {
      *(u16x8*)&ldsV[(par ^ 1) * 4096 + wv] = a;
      kc0 = kn0;
      kc1 = kn1;
    }
    __syncthreads();
  }
  // rowsum: quads partition m -> reduce across quads (lanes sharing l15)
  rs += __shfl_xor(rs, 16, 64);
  rs += __shfl_xor(rs, 32, 64);
  const float inv = __builtin_amdgcn_rcpf(rs);
  // O^T elem (d = 16jd + quad*4 + r, n = n0 + l15); OT (b, n, h*128+d)
  u16* OTb = OT + ((size_t)b * 1024 + n0 + l15) * 1024 + h * 128 + quad * 4;
#pragma unroll
  for (int jd = 0; jd < 8; ++jd) {
    u16x4 o;
#pragma unroll
    for (int r = 0; r < 4; ++r) {
      float v = oacc[jd][r] * inv;
      o[r] = fastbf(v > 0.f ? v : 0.f);
    }
    *(u16x4*)(OTb + 16 * jd) = o;
  }
}

// ---------------------------------------------------------------- launch
extern "C" void kernel_launch(void* const* d_in, const int* in_sizes, int n_in,
                              void* d_out, int out_size, void* d_ws, size_t ws_size,
                              hipStream_t stream) {
  const void* x      = d_in[0];
  const void* w_qkv  = d_in[1];
  const void* qkv_g  = d_in[2];
  const void* qkv_b  = d_in[3];
  const void* qkv_m  = d_in[4];
  const void* qkv_v  = d_in[5];
  const void* w_dw   = d_in[6];
  const void* dw_g   = d_in[7];
  const void* dw_b   = d_in[8];
  const void* dw_m   = d_in[9];
  const void* dw_v   = d_in[10];
  const void* w_proj = d_in[11];
  const void* proj_g = d_in[12];
  const void* proj_b = d_in[13];
  const void* proj_m = d_in[14];
  const void* proj_v = d_in[15];
  const void* abias  = d_in[16];

  char* ws = (char*)d_ws;
  u16*   xT      = (u16*)(ws);                   // 16,777,216 B
  u16*   qkv     = (u16*)(ws + 16777216);        // 50,331,648 B
  u16*   qT      = (u16*)(ws + 67108864);        //  8,388,608 B
  u16*   kT      = (u16*)(ws + 75497472);        //  8,388,608 B
  u16*   OT      = (u16*)(ws + 83886080);        // 33,554,432 B
  float* scl     = (float*)(ws + 117440512);     //      9,216 B
  float* shf     = (float*)(ws + 117449728);     //      9,216 B
  u16*   wqkv_c  = (u16*)(ws + 117458944);       //  1,572,864 B
  u16*   wproj_c = (u16*)(ws + 119031808);       //  1,048,576 B
  u16*   wdw_c   = (u16*)(ws + 120080384);       //      2,048 B
  u16*   ab_c    = (u16*)(ws + 120082432);       //     16,384 B
  int*   flag    = (int*)(ws + 120098816);       //         64 B
  if (ws_size < (size_t)120098880) return;

  sniff<<<1, 64, 0, stream>>>((const uint32_t*)x, flag);
  cvt_all<<<5155, 256, 0, stream>>>(w_qkv, w_proj, w_dw, abias,
                                    wqkv_c, wproj_c, wdw_c, ab_c, flag);
  prep_params<<<9, 256, 0, stream>>>(qkv_g, qkv_b, qkv_m, qkv_v, dw_g, dw_b, dw_m,
                                     dw_v, proj_g, proj_b, proj_m, proj_v, scl, shf, flag);
  transpose_x<<<dim3(16, 8, 16), 256, 0, stream>>>(x, xT, flag);
  gemm_bn<512, 128><<<dim3(8, 12, 16), 256, 0, stream>>>(wqkv_c, xT, qkv, scl, shf, 0, flag, 0);
  dwconv_pack<<<dim3(4, 8, 16), 256, 0, stream>>>(qkv, wdw_c, scl, shf, qT, kT);
  attn<<<1024, 512, 0, stream>>>(qT, kT, qkv, ab_c, OT);
  gemm_bn<1024, 64><<<dim3(16, 4, 16), 256, 0, stream>>>(wproj_c, OT, (u16*)d_out, scl, shf, 1792, flag, 1);
}